// Round 2
// baseline (242.779 us; speedup 1.0000x reference)
//
#include <hip/hip_runtime.h>
#include <math.h>

// LIF recurrence: v = v + (x_t - v)/tau; s = sigmoid(v - th); v *= (1 - s)
// x: [B=32, T=512, D=2048] fp32 -> spikes s, same shape.
//
// R3: parallel-in-time chain splitting. R1/R2 proved ILP-only latency hiding
// fails at 1 wave/SIMD (226 -> 240 us; vmcnt=63 cap defeats deep rings).
// The step map is a strong contraction: |d v_t / d v_{t-1}|
//   = 0.5*|(1-s) - g*s*(1-s)| <= ~0.55 for all g (s = sigmoid(g-1)).
// So a segment cold-started from v=0 at t0-32 converges to the true state
// within 0.55^32 * |v|max ~ 3e-8 before its first store -- six orders below
// the measured 0.0039 absmax. Split T=512 into 8 segments of 64 with a
// 32-step unstored warmup:
//   * 524288 threads = 8192 waves = 8 waves/SIMD (was 1): full TLP.
//   * warmup re-reads (+50% loads) overlap the neighbor segment's main
//     reads; the whole 134 MB input fits in the 256 MB L3 -> HBM fetch
//     stays ~134 MB. Stores are nontemporal (output never re-read).
//   * per-step math identical to the verified 226 us kernel.
// __launch_bounds__(256, 8) caps VGPR at 64 so all 8 blocks/CU co-reside;
// pipeline shrunk to U=8 double-buffer accordingly (TLP replaces ILP).

#define TAU_INV 0.5f
#define TH 1.0f

constexpr int BATCH = 32;
constexpr int TT = 512;
constexpr int DD = 2048;
constexpr int S = 8;          // segments per chain (parallel-in-time factor)
constexpr int SEG = TT / S;   // 64 stored steps per thread
constexpr int W = 32;         // warmup (unstored) steps, multiple of U
constexpr int U = 8;          // steps per chunk
static_assert(SEG % U == 0 && W % U == 0, "chunking");

__global__ __launch_bounds__(256, 8) void lif_kernel(const float* __restrict__ x,
                                                     float* __restrict__ out) {
    int tid = blockIdx.x * blockDim.x + threadIdx.x;  // [0, B*S*D)
    int d = tid & (DD - 1);
    int rest = tid >> 11;        // b*S + sg
    int sg = rest & (S - 1);     // segment index — uniform per block
    int b = rest >> 3;
    const float* xp = x + (size_t)b * TT * DD + d;
    float* op = out + (size_t)b * TT * DD + d;
    const int t0 = sg * SEG;

    float v = 0.0f;

    // Warmup: 32 unstored steps starting from v=0 at t0-32. sg is uniform
    // per block, so the branch is non-divergent; sg==0 starts exactly at
    // t=0 with the true initial state. Plain (cached) loads: these bytes
    // are also the neighbor segment's main input, keep them in L2/L3.
    if (sg != 0) {
        const float* xw = xp + (size_t)(t0 - W) * DD;
        #pragma unroll 1
        for (int c = 0; c < W / U; ++c) {
            float buf[U];
            #pragma unroll
            for (int i = 0; i < U; ++i)
                buf[i] = xw[(size_t)(c * U + i) * DD];
            #pragma unroll
            for (int i = 0; i < U; ++i) {
                v = v + (buf[i] - v) * TAU_INV;
                float s = 1.0f / (1.0f + __expf(TH - v));
                v = v * (1.0f - s);
            }
        }
    }

    // Main segment: 64 steps, 1-ahead double buffer, streamed stores.
    const float* xm = xp + (size_t)t0 * DD;
    float* om = op + (size_t)t0 * DD;
    float buf[2][U];
    #pragma unroll
    for (int i = 0; i < U; ++i)
        buf[0][i] = xm[(size_t)i * DD];

    #pragma unroll 2   // makes (c & 1) compile-time so buf[] stays in regs
    for (int c = 0; c < SEG / U; ++c) {
        const int cur = c & 1;
        const int nxt = cur ^ 1;
        if (c + 1 < SEG / U) {
            const float* xn = xm + (size_t)(c + 1) * U * DD;
            #pragma unroll
            for (int i = 0; i < U; ++i)
                buf[nxt][i] = xn[(size_t)i * DD];
        }
        float* ob = om + (size_t)c * U * DD;
        #pragma unroll
        for (int i = 0; i < U; ++i) {
            v = v + (buf[cur][i] - v) * TAU_INV;         // leak/integrate
            float s = 1.0f / (1.0f + __expf(TH - v));    // sigmoid(v - th)
            __builtin_nontemporal_store(s, ob + (size_t)i * DD);
            v = v * (1.0f - s);                           // soft reset
        }
    }
}

extern "C" void kernel_launch(void* const* d_in, const int* in_sizes, int n_in,
                              void* d_out, int out_size, void* d_ws, size_t ws_size,
                              hipStream_t stream) {
    const float* x = (const float*)d_in[0];
    float* out = (float*)d_out;
    const int threads = 256;
    const int total = BATCH * S * DD;                    // 524288 threads
    const int blocks = total / threads;                  // 2048
    lif_kernel<<<blocks, threads, 0, stream>>>(x, out);
}

// Round 4
// 238.812 us; speedup vs baseline: 1.0166x; 1.0166x over previous
//
#include <hip/hip_runtime.h>
#include <math.h>

// LIF recurrence: v = v + (x_t - v)/tau; s = sigmoid(v - th); v *= (1 - s)
// x: [B=32, T=512, D=2048] fp32 -> spikes s, same shape.
//
// R4b: width + short chain + uniform pipeline (R3 theory; compile fix:
// __builtin_nontemporal_store needs a clang ext_vector, not HIP float4).
// Counter history: R0-R2 proved ~160us of the bench is harness poison-fills;
// kernel itself was <80us in R0; R3 segmentation regressed it to 90us
// (31% HBM, 31% VALU, nothing saturated) — scalar loads (256 B/wave-instr)
// + warmup overhead ate the TLP win. Fixes, multiplicative:
//  * f32x4 vector loads/stores: each lane owns 4 consecutive d ->
//    dwordx4 (1 KiB/wave-instr, 4x width) AND 4 independent chains per
//    thread (4-way ILP on the sigmoid dependent chain).
//  * v_rcp_f32 instead of IEEE div (rel err ~2e-7, invisible under the
//    0.0039 absmax floor): cuts ~7 VALU ops + ~20 dependent cycles/step.
//  * one fully-unrolled 12-chunk pipeline (4 warmup + 8 stored), ring of 3,
//    prefetch distance 2 (16 dwordx4 in flight/wave). sg==0 runs a dummy
//    warmup on its own data then resets v=0 -> uniform code path, no
//    early-finish tail.
// Parallel-in-time correctness: step map is a contraction (|dv_t/dv_{t-1}|
// <= ~0.55); 32-step cold-start warmup error <= 0.55^32*|v|max ~ 3e-8.
// Geometry: 131072 threads = 2048 waves = 2 waves/SIMD. Traffic = 201 MB
// reads (1.5x ideal) + 134 MB writes = 335 MB -> HBM roofline ~51 us.

#define TAU_INV 0.5f
#define TH 1.0f

typedef __attribute__((ext_vector_type(4))) float f32x4;

constexpr int BATCH = 32;
constexpr int TT = 512;
constexpr int DD = 2048;
constexpr int S = 8;            // segments per chain
constexpr int SEG = TT / S;     // 64 stored steps per thread
constexpr int W = 32;           // warmup steps
constexpr int U = 8;            // steps per chunk
constexpr int NC_W = W / U;     // 4 warmup chunks
constexpr int NC_M = SEG / U;   // 8 stored chunks
constexpr int NC = NC_W + NC_M; // 12 chunks total
constexpr int PD = 2;           // prefetch distance (chunks)
constexpr int DEPTH = PD + 1;   // ring slots

__global__ __launch_bounds__(256, 2) void lif_kernel(const float* __restrict__ x,
                                                     float* __restrict__ out) {
    int tid = blockIdx.x * blockDim.x + threadIdx.x;  // [0, B*S*D/4)
    int d4 = tid & 511;          // group of 4 d-values
    int sg = (tid >> 9) & 7;     // segment — uniform per block (256 thr)
    int b = tid >> 12;
    int d = d4 * 4;
    const int t0 = sg * SEG;
    const bool warm = (sg != 0);

    // Warmup chunks read [t0-32, t0) for sg>0; sg==0 reads its own
    // [t0, t0+32) as a dummy (uniform code path) and resets v after.
    const float* xw = x + ((size_t)b * TT + (warm ? t0 - W : t0)) * DD + d;
    const float* xm = x + ((size_t)b * TT + t0) * DD + d;
    float* om = out + ((size_t)b * TT + t0) * DD + d;

    f32x4 buf[DEPTH][U];

    auto src = [&](int c) -> const f32x4* {
        // c is compile-time under full unroll; ternary folds away.
        return (c < NC_W)
                   ? reinterpret_cast<const f32x4*>(xw + (size_t)c * U * DD)
                   : reinterpret_cast<const f32x4*>(xm + (size_t)(c - NC_W) * U * DD);
    };

    // Prologue: issue chunks 0..PD-1.
    #pragma unroll
    for (int c = 0; c < PD; ++c) {
        const f32x4* sp = src(c);
        #pragma unroll
        for (int i = 0; i < U; ++i)
            buf[c][i] = sp[(size_t)i * (DD / 4)];
    }

    float v0 = 0.0f, v1 = 0.0f, v2 = 0.0f, v3 = 0.0f;

    #pragma unroll
    for (int c = 0; c < NC; ++c) {
        const int cur = c % DEPTH;

        // Prefetch chunk c+PD: lands ~2 compute-phases later.
        if (c + PD < NC) {
            const int ps = (c + PD) % DEPTH;
            const f32x4* sp = src(c + PD);
            #pragma unroll
            for (int i = 0; i < U; ++i)
                buf[ps][i] = sp[(size_t)i * (DD / 4)];
        }

        // Compute chunk c: 8 steps x 4 independent chains.
        #pragma unroll
        for (int i = 0; i < U; ++i) {
            float in0 = buf[cur][i].x, in1 = buf[cur][i].y;
            float in2 = buf[cur][i].z, in3 = buf[cur][i].w;
            float s0, s1, s2, s3;
            // step: v += (in-v)/tau; s = 1/(1+exp(th-v)); v *= (1-s)
            v0 = v0 + (in0 - v0) * TAU_INV;
            v1 = v1 + (in1 - v1) * TAU_INV;
            v2 = v2 + (in2 - v2) * TAU_INV;
            v3 = v3 + (in3 - v3) * TAU_INV;
            s0 = __builtin_amdgcn_rcpf(1.0f + __expf(TH - v0));
            s1 = __builtin_amdgcn_rcpf(1.0f + __expf(TH - v1));
            s2 = __builtin_amdgcn_rcpf(1.0f + __expf(TH - v2));
            s3 = __builtin_amdgcn_rcpf(1.0f + __expf(TH - v3));
            v0 = v0 * (1.0f - s0);
            v1 = v1 * (1.0f - s1);
            v2 = v2 * (1.0f - s2);
            v3 = v3 * (1.0f - s3);
            if (c >= NC_W) {
                f32x4 sv = {s0, s1, s2, s3};
                f32x4* op = reinterpret_cast<f32x4*>(
                    om + (size_t)((c - NC_W) * U + i) * DD);
                __builtin_nontemporal_store(sv, op);
            }
        }

        // After the warmup chunks: sg==0's warmup was a dummy — reset to
        // the true initial state v=0. Uniform per block, no divergence.
        if (c == NC_W - 1) {
            if (!warm) { v0 = 0.0f; v1 = 0.0f; v2 = 0.0f; v3 = 0.0f; }
        }
    }
}

extern "C" void kernel_launch(void* const* d_in, const int* in_sizes, int n_in,
                              void* d_out, int out_size, void* d_ws, size_t ws_size,
                              hipStream_t stream) {
    const float* x = (const float*)d_in[0];
    float* out = (float*)d_out;
    const int threads = 256;
    const int total = BATCH * S * (DD / 4);              // 131072 threads
    const int blocks = total / threads;                  // 512
    lif_kernel<<<blocks, threads, 0, stream>>>(x, out);
}